// Round 1
// baseline (29.576 us; speedup 1.0000x reference)
//
#include <hip/hip_runtime.h>

// Fused two-stage shift-conv for x:(1,1024,7,7) f32, w1:(32,64,3), w2:(32,16,3).
//
// Stage 1: t4[k,j2,m,n] = sum_{i=0..63, j=0..2 valid} x[(i*16+j2)*49 + hh(m,j)*7 + n] * w1[k*192+i*3+j]
//          where hh(m,j) = (m+j+5)%7 (roll(+1,H) folded into the H-window),
//          valid(j): j=0 iff m>=1, j=1 always, j=2 iff m<=5.
// Stage 2: out[(i2*32+k)*49 + m*7 + n] = sum_{j2=0..15, k2=0..2, 0<=n+k2-1<7}
//          t4[k,j2,m,n+k2-1] * w2[i2*48+j2*3+k2]
//
// Block per (m,k): computes t4 row [k,:,m,:] (112 vals) once into LDS, then the
// 224 outputs (i2=0..31, n=0..6) that depend on it. No global intermediate.

__global__ __launch_bounds__(128, 1) void fused_shift_conv(
    const float* __restrict__ x,
    const float* __restrict__ w1,
    const float* __restrict__ w2,
    float* __restrict__ out)
{
    __shared__ float t4s[16 * 8];   // [j2][n], stride 8 (n<7)

    const int m   = blockIdx.x;     // 0..6  (output row)
    const int k   = blockIdx.y;     // 0..31 (stage-1 output channel)
    const int tid = threadIdx.x;

    // roll(+1) + H-window constants (block-uniform)
    const bool v0 = (m >= 1);
    const bool v2 = (m <= 5);
    const int  r0 = ((m + 5) % 7) * 7;   // source row offset for j=0
    const int  r1 = ((m + 6) % 7) * 7;   // j=1
    const int  r2 = m * 7;               // j=2 ((m+7)%7 == m)

    // ---- Phase 1: t4 row -> LDS (112 active threads) ----
    if (tid < 112) {
        const int j2 = tid / 7;
        const int n  = tid - j2 * 7;
        const float* __restrict__ wk = w1 + k * 192;   // block-uniform -> scalar loads
        const float* __restrict__ xb = x + j2 * 49 + n;
        float s = 0.f;
        #pragma unroll 8
        for (int i = 0; i < 64; ++i) {
            const float* xi = xb + i * 784;            // (i*16)*49
            const float wa = wk[3 * i + 0];
            const float wb = wk[3 * i + 1];
            const float wc = wk[3 * i + 2];
            if (v0) s += xi[r0] * wa;                  // uniform predicate
            s += xi[r1] * wb;
            if (v2) s += xi[r2] * wc;                  // uniform predicate
        }
        t4s[j2 * 8 + n] = s;
    }
    __syncthreads();

    // ---- Phase 2: 224 outputs, 128 threads -> up to 2 each ----
    #pragma unroll
    for (int t = 0; t < 2; ++t) {
        const int oidx = tid + t * 128;
        if (oidx < 224) {
            const int i2 = oidx / 7;
            const int n  = oidx - i2 * 7;

            // preload this i2's 48 w2 coeffs as 12 float4 (16B-aligned: 48 floats/row)
            float wr[48];
            const float4* w4 = reinterpret_cast<const float4*>(w2 + i2 * 48);
            #pragma unroll
            for (int q = 0; q < 12; ++q)
                reinterpret_cast<float4*>(wr)[q] = w4[q];

            float acc = 0.f;
            #pragma unroll
            for (int j2 = 0; j2 < 16; ++j2) {
                const float mid = t4s[j2 * 8 + n];
                const float lo  = (n >= 1) ? t4s[j2 * 8 + n - 1] : 0.f;  // k2=0
                const float hi  = (n <= 5) ? t4s[j2 * 8 + n + 1] : 0.f;  // k2=2
                acc += lo  * wr[j2 * 3 + 0]
                     + mid * wr[j2 * 3 + 1]
                     + hi  * wr[j2 * 3 + 2];
            }
            out[(i2 * 32 + k) * 49 + m * 7 + n] = acc;
        }
    }
}

extern "C" void kernel_launch(void* const* d_in, const int* in_sizes, int n_in,
                              void* d_out, int out_size, void* d_ws, size_t ws_size,
                              hipStream_t stream) {
    const float* x  = (const float*)d_in[0];   // (1,1024,7,7)
    const float* w1 = (const float*)d_in[1];   // (32,64,3)
    const float* w2 = (const float*)d_in[2];   // (32,16,3)
    float* out = (float*)d_out;                // (1,1024,7,7)

    dim3 grid(7, 32);   // blockIdx.x = m, blockIdx.y = k
    fused_shift_conv<<<grid, 128, 0, stream>>>(x, w1, w2, out);
}

// Round 2
// 12.108 us; speedup vs baseline: 2.4426x; 2.4426x over previous
//
#include <hip/hip_runtime.h>

// Fused two-stage shift-conv for x:(1,1024,7,7) f32, w1:(32,64,3), w2:(32,16,3).
//
// Stage 1: t4[k,j2,m,n] = sum_{i=0..63, j valid} x[(i*16+j2)*49 + hh(m,j)*7 + n] * w1[k,i,j]
//          hh(m,j) = (m+j+5)%7  (roll(+1,H) folded into the H-window)
//          valid: j=0 iff m>=1, j=1 always, j=2 iff m<=5.
// Stage 2: out[(i2*32+k)*49 + m*7 + n] = sum_{j2<16, k2<3, 0<=n+k2-1<7}
//          t4[k,j2,m,n+k2-1] * w2[i2,j2,k2]
//
// Block per (m,k), 512 threads: phase 1 splits the i-reduction 4 ways
// (half = tid>>7 covers i in [half*16, half*16+16)), giving 8 waves/block
// (1792 waves total, ~7/CU) and a 48-load chain per thread instead of 192.
// Rows r0/r1/r2 are always legal addresses (mod-7 row within the channel
// slab), so the inner loop is branch-free; H-window validity is applied
// once to the three partial accumulators. Each x element is still read
// exactly once per block.

__global__ __launch_bounds__(512, 1) void fused_shift_conv(
    const float* __restrict__ x,
    const float* __restrict__ w1,
    const float* __restrict__ w2,
    float* __restrict__ out)
{
    __shared__ float part[4][128];   // [ihalf][j2*8+n], stride-8 padded
    __shared__ float t4s[128];       // [j2*8+n]

    const int m   = blockIdx.x;      // 0..6
    const int k   = blockIdx.y;      // 0..31
    const int tid = threadIdx.x;

    const bool v0 = (m >= 1);
    const bool v2 = (m <= 5);
    const int  r0 = ((m + 5) % 7) * 7;   // source row offset, j=0
    const int  r1 = ((m + 6) % 7) * 7;   // j=1
    const int  r2 = m * 7;               // j=2

    const int half = tid >> 7;           // 0..3 (wave-uniform: 2 waves per half)
    const int r    = tid & 127;

    // ---- Phase 1: partial t4 over i in [half*16, half*16+16) ----
    if (r < 112) {
        const int j2 = r / 7;
        const int n  = r - j2 * 7;

        // preload this (k, half)'s 48 w1 coeffs as 12 float4 into registers
        float wr[48];
        const float4* wv = reinterpret_cast<const float4*>(w1 + k * 192 + half * 48);
        #pragma unroll
        for (int q = 0; q < 12; ++q)
            reinterpret_cast<float4*>(wr)[q] = wv[q];

        // channel = (half*16 + ii)*16 + j2 = half*256 + ii*16 + j2
        const float* __restrict__ xb = x + (half * 256 + j2) * 49 + n;
        float s0 = 0.f, s1 = 0.f, s2 = 0.f;
        #pragma unroll
        for (int ii = 0; ii < 16; ++ii) {
            const float* xi = xb + ii * 784;    // ii*16*49
            s0 += xi[r0] * wr[3 * ii + 0];
            s1 += xi[r1] * wr[3 * ii + 1];
            s2 += xi[r2] * wr[3 * ii + 2];
        }
        part[half][j2 * 8 + n] = (v0 ? s0 : 0.f) + s1 + (v2 ? s2 : 0.f);
    }
    __syncthreads();

    // ---- Combine the 4 i-partials ----
    if (tid < 112) {
        const int j2  = tid / 7;
        const int n   = tid - j2 * 7;
        const int idx = j2 * 8 + n;
        t4s[idx] = part[0][idx] + part[1][idx] + part[2][idx] + part[3][idx];
    }
    __syncthreads();

    // ---- Phase 2: 224 outputs, one per thread ----
    if (tid < 224) {
        const int i2 = tid / 7;
        const int n  = tid - i2 * 7;

        float wr[48];
        const float4* w4 = reinterpret_cast<const float4*>(w2 + i2 * 48);
        #pragma unroll
        for (int q = 0; q < 12; ++q)
            reinterpret_cast<float4*>(wr)[q] = w4[q];

        float acc = 0.f;
        #pragma unroll
        for (int j2 = 0; j2 < 16; ++j2) {
            const float mid = t4s[j2 * 8 + n];
            const float lo  = (n >= 1) ? t4s[j2 * 8 + n - 1] : 0.f;  // k2=0
            const float hi  = (n <= 5) ? t4s[j2 * 8 + n + 1] : 0.f;  // k2=2
            acc += lo  * wr[j2 * 3 + 0]
                 + mid * wr[j2 * 3 + 1]
                 + hi  * wr[j2 * 3 + 2];
        }
        out[(i2 * 32 + k) * 49 + m * 7 + n] = acc;
    }
}

extern "C" void kernel_launch(void* const* d_in, const int* in_sizes, int n_in,
                              void* d_out, int out_size, void* d_ws, size_t ws_size,
                              hipStream_t stream) {
    const float* x  = (const float*)d_in[0];   // (1,1024,7,7)
    const float* w1 = (const float*)d_in[1];   // (32,64,3)
    const float* w2 = (const float*)d_in[2];   // (32,16,3)
    float* out = (float*)d_out;                // (1,1024,7,7)

    dim3 grid(7, 32);   // blockIdx.x = m, blockIdx.y = k
    fused_shift_conv<<<grid, 512, 0, stream>>>(x, w1, w2, out);
}

// Round 3
// 11.665 us; speedup vs baseline: 2.5354x; 1.0380x over previous
//
#include <hip/hip_runtime.h>

// Fused two-stage shift-conv for x:(1,1024,7,7) f32, w1:(32,64,3), w2:(32,16,3).
//
// Stage 1: t4[k,j2,m,n] = sum_{i=0..63, j valid} x[(i*16+j2)*49 + hh(m,j)*7 + n] * w1[k,i,j]
//          hh(m,j) = (m+j+5)%7  (roll(+1,H) folded into the H-window)
//          valid: j=0 iff m>=1, j=1 always, j=2 iff m<=5.
// Stage 2: out[(i2*32+k)*49 + m*7 + n] = sum_{j2<16, k2<3, 0<=n+k2-1<7}
//          t4[k,j2,m,n+k2-1] * w2[i2,j2,k2]
//
// Block per (m,k), 1024 threads: phase 1 splits the i-reduction 8 ways
// (half = tid>>7 covers i in [half*8, half*8+8)), so each thread's global
// load chain is 24 independent L2-hit loads; 16 waves/block for latency
// hiding. `half` is wave-uniform -> readfirstlane makes the w1 pointer
// scalar so weight loads go down the SMEM pipe, not VMEM.

__global__ __launch_bounds__(1024, 1) void fused_shift_conv(
    const float* __restrict__ x,
    const float* __restrict__ w1,
    const float* __restrict__ w2,
    float* __restrict__ out)
{
    __shared__ float part[8][128];   // [ihalf][j2*8+n], stride-8 padded
    __shared__ float t4s[128];       // [j2*8+n]

    const int m   = blockIdx.x;      // 0..6
    const int k   = blockIdx.y;      // 0..31
    const int tid = threadIdx.x;

    const bool v0 = (m >= 1);
    const bool v2 = (m <= 5);
    const int  r0 = ((m + 5) % 7) * 7;   // source row offset, j=0
    const int  r1 = ((m + 6) % 7) * 7;   // j=1
    const int  r2 = m * 7;               // j=2

    // half = tid>>7 is uniform across each wave (2 waves per half value)
    const int half = __builtin_amdgcn_readfirstlane(tid >> 7);   // 0..7, SGPR
    const int r    = tid & 127;

    // ---- Phase 1: partial t4 over i in [half*8, half*8+8) ----
    if (r < 112) {
        const int j2 = r / 7;
        const int n  = r - j2 * 7;

        // this (k, half)'s 24 w1 coeffs; uniform pointer -> scalar loads
        const float* __restrict__ wk = w1 + k * 192 + half * 24;

        // channel = (half*8 + ii)*16 + j2 = half*128 + ii*16 + j2
        const float* __restrict__ xb = x + (half * 128 + j2) * 49 + n;
        float s0 = 0.f, s1 = 0.f, s2 = 0.f;
        #pragma unroll
        for (int ii = 0; ii < 8; ++ii) {
            const float* xi = xb + ii * 784;    // ii*16*49
            s0 += xi[r0] * wk[3 * ii + 0];
            s1 += xi[r1] * wk[3 * ii + 1];
            s2 += xi[r2] * wk[3 * ii + 2];
        }
        part[half][j2 * 8 + n] = (v0 ? s0 : 0.f) + s1 + (v2 ? s2 : 0.f);
    }
    __syncthreads();

    // ---- Combine the 8 i-partials ----
    if (tid < 112) {
        const int j2  = tid / 7;
        const int n   = tid - j2 * 7;
        const int idx = j2 * 8 + n;
        float s = 0.f;
        #pragma unroll
        for (int h = 0; h < 8; ++h) s += part[h][idx];
        t4s[idx] = s;
    }
    __syncthreads();

    // ---- Phase 2: 224 outputs, one per thread ----
    if (tid < 224) {
        const int i2 = tid / 7;
        const int n  = tid - i2 * 7;

        float wr[48];
        const float4* w4 = reinterpret_cast<const float4*>(w2 + i2 * 48);
        #pragma unroll
        for (int q = 0; q < 12; ++q)
            reinterpret_cast<float4*>(wr)[q] = w4[q];

        float acc = 0.f;
        #pragma unroll
        for (int j2 = 0; j2 < 16; ++j2) {
            const float mid = t4s[j2 * 8 + n];
            const float lo  = (n >= 1) ? t4s[j2 * 8 + n - 1] : 0.f;  // k2=0
            const float hi  = (n <= 5) ? t4s[j2 * 8 + n + 1] : 0.f;  // k2=2
            acc += lo  * wr[j2 * 3 + 0]
                 + mid * wr[j2 * 3 + 1]
                 + hi  * wr[j2 * 3 + 2];
        }
        out[(i2 * 32 + k) * 49 + m * 7 + n] = acc;
    }
}

extern "C" void kernel_launch(void* const* d_in, const int* in_sizes, int n_in,
                              void* d_out, int out_size, void* d_ws, size_t ws_size,
                              hipStream_t stream) {
    const float* x  = (const float*)d_in[0];   // (1,1024,7,7)
    const float* w1 = (const float*)d_in[1];   // (32,64,3)
    const float* w2 = (const float*)d_in[2];   // (32,16,3)
    float* out = (float*)d_out;                // (1,1024,7,7)

    dim3 grid(7, 32);   // blockIdx.x = m, blockIdx.y = k
    fused_shift_conv<<<grid, 1024, 0, stream>>>(x, w1, w2, out);
}

// Round 4
// 11.656 us; speedup vs baseline: 2.5374x; 1.0008x over previous
//
#include <hip/hip_runtime.h>

// Fused two-stage shift-conv for x:(1,1024,7,7) f32, w1:(32,64,3), w2:(32,16,3).
//
// Stage 1: t4[k,j2,m,n] = sum_{i=0..63, j valid} x[(i*16+j2)*49 + hh(m,j)*7 + n] * w1[k,i,j]
//          hh(m,j) = (m+j+5)%7  (roll(+1,H) folded into the H-window)
//          valid: j=0 iff m>=1, j=1 always, j=2 iff m<=5.
// Stage 2: out[(i2*32+k)*49 + m*7 + n] = sum_{j2<16, k2<3, 0<=n+k2-1<7}
//          t4[k,j2,m,n+k2-1] * w2[i2,j2,k2]
//
// Block per (m,k), 1024 threads, latency-floor-tuned:
//  - phase-2's w2 loads (12 x float4, t4-independent) are ISSUED at kernel
//    start; their s_waitcnt lands after the barriers, so the L2 round-trip
//    hides under phase 1 instead of sitting on the critical path.
//  - phase 1 splits the i-reduction 8 ways (24 independent L2-hit loads per
//    thread, one waitcnt window); w1 via wave-uniform scalar loads.
//  - branch-free inner loop; H-window validity folded into 3 accumulators.

__global__ __launch_bounds__(1024, 1) void fused_shift_conv(
    const float* __restrict__ x,
    const float* __restrict__ w1,
    const float* __restrict__ w2,
    float* __restrict__ out)
{
    __shared__ float part[8][128];   // [ihalf][j2*8+n], stride-8 padded
    __shared__ float t4s[128];       // [j2*8+n]

    const int m   = blockIdx.x;      // 0..6
    const int k   = blockIdx.y;      // 0..31
    const int tid = threadIdx.x;

    // ---- Early issue: phase-2 weights (independent of everything else).
    // Loads are issued here; the wait for them lands after the barriers.
    const int i2 = tid / 7;          // valid only when tid < 224
    const int n2 = tid - i2 * 7;
    float4 wreg[12];
    if (tid < 224) {
        const float4* __restrict__ w4 = reinterpret_cast<const float4*>(w2 + i2 * 48);
        #pragma unroll
        for (int q = 0; q < 12; ++q) wreg[q] = w4[q];
    }

    const bool v0 = (m >= 1);
    const bool v2 = (m <= 5);
    const int  r0 = ((m + 5) % 7) * 7;   // source row offset, j=0
    const int  r1 = ((m + 6) % 7) * 7;   // j=1
    const int  r2 = m * 7;               // j=2

    // half = tid>>7 is uniform across each wave (2 waves per half value)
    const int half = __builtin_amdgcn_readfirstlane(tid >> 7);   // 0..7, SGPR
    const int r    = tid & 127;

    // ---- Phase 1: partial t4 over i in [half*8, half*8+8) ----
    if (r < 112) {
        const int j2 = r / 7;
        const int n  = r - j2 * 7;

        // this (k, half)'s 24 w1 coeffs; uniform pointer -> scalar loads
        const float* __restrict__ wk = w1 + k * 192 + half * 24;

        // channel = (half*8 + ii)*16 + j2 = half*128 + ii*16 + j2
        const float* __restrict__ xb = x + (half * 128 + j2) * 49 + n;
        float s0 = 0.f, s1 = 0.f, s2 = 0.f;
        #pragma unroll
        for (int ii = 0; ii < 8; ++ii) {
            const float* xi = xb + ii * 784;    // ii*16*49
            s0 += xi[r0] * wk[3 * ii + 0];
            s1 += xi[r1] * wk[3 * ii + 1];
            s2 += xi[r2] * wk[3 * ii + 2];
        }
        part[half][j2 * 8 + n] = (v0 ? s0 : 0.f) + s1 + (v2 ? s2 : 0.f);
    }
    __syncthreads();

    // ---- Combine the 8 i-partials ----
    if (tid < 112) {
        const int j2  = tid / 7;
        const int n   = tid - j2 * 7;
        const int idx = j2 * 8 + n;
        float s = 0.f;
        #pragma unroll
        for (int h = 0; h < 8; ++h) s += part[h][idx];
        t4s[idx] = s;
    }
    __syncthreads();

    // ---- Phase 2: 224 outputs, one per thread (w2 already in registers) ----
    if (tid < 224) {
        const float* wr = reinterpret_cast<const float*>(wreg);
        float acc = 0.f;
        #pragma unroll
        for (int j2 = 0; j2 < 16; ++j2) {
            const float mid = t4s[j2 * 8 + n2];
            const float lo  = (n2 >= 1) ? t4s[j2 * 8 + n2 - 1] : 0.f;  // k2=0
            const float hi  = (n2 <= 5) ? t4s[j2 * 8 + n2 + 1] : 0.f;  // k2=2
            acc += lo  * wr[j2 * 3 + 0]
                 + mid * wr[j2 * 3 + 1]
                 + hi  * wr[j2 * 3 + 2];
        }
        out[(i2 * 32 + k) * 49 + m * 7 + n2] = acc;
    }
}

extern "C" void kernel_launch(void* const* d_in, const int* in_sizes, int n_in,
                              void* d_out, int out_size, void* d_ws, size_t ws_size,
                              hipStream_t stream) {
    const float* x  = (const float*)d_in[0];   // (1,1024,7,7)
    const float* w1 = (const float*)d_in[1];   // (32,64,3)
    const float* w2 = (const float*)d_in[2];   // (32,16,3)
    float* out = (float*)d_out;                // (1,1024,7,7)

    dim3 grid(7, 32);   // blockIdx.x = m, blockIdx.y = k
    fused_shift_conv<<<grid, 1024, 0, stream>>>(x, w1, w2, out);
}